// Round 3
// baseline (524.207 us; speedup 1.0000x reference)
//
#include <hip/hip_runtime.h>

// GraphSAGE: 2x SAGEConv(mean) + Linear + softmax. fp32 throughout.
// Pipeline: CSR build (count / 3-phase scan / fill)
//           -> aggregate -> linear1(+ReLU) -> aggregate -> fused linear2+out+softmax.
// Linear tiling: block = 32 nodes x 128 cols; thread = 2 nodes x 8 cols (acc[16]).
// Per k4 per thread: 4 ds_read_b128 (48cyc) vs 128 FMA (256cyc) -> VALU-pipe-bound.

#define CHUNK 2048   // elements per scan block (256 threads x 8)

__global__ void count_kernel(const int* __restrict__ dst, int* __restrict__ cnt, int E, int N) {
    int e = blockIdx.x * blockDim.x + threadIdx.x;
    if (e < E) {
        int d = dst[e];
        if ((unsigned)d < (unsigned)N) atomicAdd(&cnt[d], 1);
    }
}

// Phase A: per-chunk sums.
__global__ __launch_bounds__(256) void scan_partial_kernel(const int* __restrict__ cnt,
                                                           int* __restrict__ partial, int n) {
    __shared__ int ws[4];
    int base = blockIdx.x * CHUNK + (int)threadIdx.x * 8;
    int s = 0;
#pragma unroll
    for (int u = 0; u < 8; ++u) {
        int i = base + u;
        if (i < n) s += cnt[i];
    }
#pragma unroll
    for (int o = 32; o; o >>= 1) s += __shfl_xor(s, o, 64);
    int lane = threadIdx.x & 63, wv = threadIdx.x >> 6;
    if (lane == 0) ws[wv] = s;
    __syncthreads();
    if (threadIdx.x == 0) partial[blockIdx.x] = ws[0] + ws[1] + ws[2] + ws[3];
}

// Phase B: 1 wave scans the partials (P ~ 25), writes per-chunk bases + off[n].
__global__ void scan_base_kernel(const int* __restrict__ partial, int* __restrict__ baseArr,
                                 int* __restrict__ off, int P, int n) {
    int lane = threadIdx.x;   // blockDim = 64
    int running = 0;
    for (int b0 = 0; b0 < P; b0 += 64) {
        int i = b0 + lane;
        int v = (i < P) ? partial[i] : 0;
        int s = v;
#pragma unroll
        for (int o = 1; o < 64; o <<= 1) {
            int t = __shfl_up(s, o, 64);
            if (lane >= o) s += t;
        }
        if (i < P) baseArr[i] = running + s - v;
        running += __shfl(s, 63, 64);
    }
    if (lane == 0) off[n] = running;
}

// Phase C: per-chunk exclusive scan + base.
__global__ __launch_bounds__(256) void scan_chunk_kernel(const int* __restrict__ cnt,
                                                         const int* __restrict__ baseArr,
                                                         int* __restrict__ off, int n) {
    __shared__ int wsum[4];
    int lane = threadIdx.x & 63, wv = threadIdx.x >> 6;
    int i0 = blockIdx.x * CHUNK + (int)threadIdx.x * 8;
    int v[8];
    int ts = 0;
#pragma unroll
    for (int u = 0; u < 8; ++u) {
        int i = i0 + u;
        v[u] = (i < n) ? cnt[i] : 0;
        ts += v[u];
    }
    int s = ts;
#pragma unroll
    for (int o = 1; o < 64; o <<= 1) {
        int t = __shfl_up(s, o, 64);
        if (lane >= o) s += t;
    }
    if (lane == 63) wsum[wv] = s;
    __syncthreads();
    int run = baseArr[blockIdx.x];
    for (int w = 0; w < wv; ++w) run += wsum[w];
    run += s - ts;   // exclusive prefix for this thread's first element
#pragma unroll
    for (int u = 0; u < 8; ++u) {
        int i = i0 + u;
        if (i < n) off[i] = run;
        run += v[u];
    }
}

__global__ void fill_kernel(const int* __restrict__ src, const int* __restrict__ dstp,
                            const int* __restrict__ off, int* __restrict__ cursor,
                            int* __restrict__ csr, int E, int N) {
    int e = blockIdx.x * blockDim.x + threadIdx.x;
    if (e < E) {
        int d = dstp[e];
        int s = src[e];
        if ((unsigned)d < (unsigned)N) {
            int pos = atomicAdd(&cursor[d], 1);
            csr[off[d] + pos] = ((unsigned)s < (unsigned)N) ? s : 0;
        }
    }
}

// Mean aggregation: 32 lanes per node, float4 per lane, 2 independent accumulators.
__global__ void aggregate_kernel(const float* __restrict__ h, const int* __restrict__ off,
                                 const int* __restrict__ csr, float* __restrict__ agg, int N) {
    int t = blockIdx.x * blockDim.x + threadIdx.x;
    int node = t >> 5;
    int lane = t & 31;
    if (node >= N) return;
    int s0 = off[node], s1 = off[node + 1];
    const float4* h4 = (const float4*)h;
    float4 a0 = make_float4(0.f, 0.f, 0.f, 0.f);
    float4 a1 = make_float4(0.f, 0.f, 0.f, 0.f);
    int e = s0;
    for (; e + 2 <= s1; e += 2) {
        int i0 = csr[e], i1 = csr[e + 1];
        float4 v0 = h4[(size_t)i0 * 32 + lane];
        float4 v1 = h4[(size_t)i1 * 32 + lane];
        a0.x += v0.x; a0.y += v0.y; a0.z += v0.z; a0.w += v0.w;
        a1.x += v1.x; a1.y += v1.y; a1.z += v1.z; a1.w += v1.w;
    }
    if (e < s1) {
        int i0 = csr[e];
        float4 v0 = h4[(size_t)i0 * 32 + lane];
        a0.x += v0.x; a0.y += v0.y; a0.z += v0.z; a0.w += v0.w;
    }
    float inv = 1.0f / (float)max(s1 - s0, 1);
    ((float4*)agg)[(size_t)node * 32 + lane] = make_float4(
        (a0.x + a1.x) * inv, (a0.y + a1.y) * inv, (a0.z + a1.z) * inv, (a0.w + a1.w) * inv);
}

// Shared GEMM core: 32-node tile in LDS, thread = 2 nodes x 8 cols.
// c = tid & 15 (cols c*8..c*8+7), ng = tid >> 4 (nodes ng*2, ng*2+1).
__device__ __forceinline__ void sage_tile_gemm(
        const float (*sA)[128], const float (*sB)[128],
        const float* __restrict__ Wl, const float* __restrict__ Wr,
        const float* __restrict__ b, int tid, float acc[2][8]) {
    int c = tid & 15;
    int ng = tid >> 4;
    int n0 = ng * 2, n1 = n0 + 1;
    const float4* Wl4 = (const float4*)Wl;
    const float4* Wr4 = (const float4*)Wr;
    float bj[8];
#pragma unroll
    for (int cc = 0; cc < 8; ++cc) bj[cc] = b[c * 8 + cc];
#pragma unroll
    for (int q = 0; q < 2; ++q)
#pragma unroll
        for (int cc = 0; cc < 8; ++cc) acc[q][cc] = bj[cc];

    for (int k4 = 0; k4 < 32; ++k4) {
        float4 a0 = ((const float4*)sA[n0])[k4];
        float4 a1 = ((const float4*)sA[n1])[k4];
        float4 h0 = ((const float4*)sB[n0])[k4];
        float4 h1 = ((const float4*)sB[n1])[k4];
        const float* a0p = (const float*)&a0;
        const float* a1p = (const float*)&a1;
        const float* h0p = (const float*)&h0;
        const float* h1p = (const float*)&h1;
#pragma unroll
        for (int u = 0; u < 4; ++u) {
            int k = k4 * 4 + u;
            float4 wl0 = Wl4[k * 32 + c * 2];
            float4 wl1 = Wl4[k * 32 + c * 2 + 1];
            float4 wr0 = Wr4[k * 32 + c * 2];
            float4 wr1 = Wr4[k * 32 + c * 2 + 1];
            const float* wlp = (const float*)&wl0;   // wl0,wl1 contiguous? no — unpack both
            float wl[8] = {wl0.x, wl0.y, wl0.z, wl0.w, wl1.x, wl1.y, wl1.z, wl1.w};
            float wr[8] = {wr0.x, wr0.y, wr0.z, wr0.w, wr1.x, wr1.y, wr1.z, wr1.w};
            (void)wlp;
            float a0u = a0p[u], a1u = a1p[u], h0u = h0p[u], h1u = h1p[u];
#pragma unroll
            for (int cc = 0; cc < 8; ++cc) {
                acc[0][cc] += a0u * wl[cc] + h0u * wr[cc];
                acc[1][cc] += a1u * wl[cc] + h1u * wr[cc];
            }
        }
    }
}

// hout = relu(agg @ Wl + hin @ Wr + b).
__global__ __launch_bounds__(256) void sage_linear_kernel(
        const float* __restrict__ agg, const float* __restrict__ hin,
        const float* __restrict__ Wl, const float* __restrict__ Wr,
        const float* __restrict__ b, float* __restrict__ hout, int N) {
    __shared__ float sA[32][128];
    __shared__ float sB[32][128];
    int node0 = blockIdx.x * 32;
    const float4* agg4 = (const float4*)agg;
    const float4* hin4 = (const float4*)hin;
    for (int i = threadIdx.x; i < 32 * 32; i += 256) {
        int nn = i >> 5, f4 = i & 31;
        int node = node0 + nn;
        float4 a = make_float4(0.f, 0.f, 0.f, 0.f), hh = a;
        if (node < N) { a = agg4[(size_t)node * 32 + f4]; hh = hin4[(size_t)node * 32 + f4]; }
        ((float4*)sA[nn])[f4] = a;
        ((float4*)sB[nn])[f4] = hh;
    }
    __syncthreads();
    float acc[2][8];
    sage_tile_gemm(sA, sB, Wl, Wr, b, (int)threadIdx.x, acc);
    int c = threadIdx.x & 15;
    int ng = threadIdx.x >> 4;
#pragma unroll
    for (int q = 0; q < 2; ++q) {
        int node = node0 + ng * 2 + q;
        if (node < N) {
            float4 o0 = make_float4(fmaxf(acc[q][0], 0.f), fmaxf(acc[q][1], 0.f),
                                    fmaxf(acc[q][2], 0.f), fmaxf(acc[q][3], 0.f));
            float4 o1 = make_float4(fmaxf(acc[q][4], 0.f), fmaxf(acc[q][5], 0.f),
                                    fmaxf(acc[q][6], 0.f), fmaxf(acc[q][7], 0.f));
            float4* dst = (float4*)(hout + (size_t)node * 128 + c * 8);
            dst[0] = o0;
            dst[1] = o1;
        }
    }
}

// Fused layer 2 + output projection + softmax.
__global__ __launch_bounds__(256) void sage_linear_out_kernel(
        const float* __restrict__ agg, const float* __restrict__ hin,
        const float* __restrict__ Wl, const float* __restrict__ Wr,
        const float* __restrict__ b, const float* __restrict__ Wout,
        const float* __restrict__ bout, float* __restrict__ out, int N) {
    __shared__ float sA[32][128];
    __shared__ float sB[32][128];
    int node0 = blockIdx.x * 32;
    const float4* agg4 = (const float4*)agg;
    const float4* hin4 = (const float4*)hin;
    for (int i = threadIdx.x; i < 32 * 32; i += 256) {
        int nn = i >> 5, f4 = i & 31;
        int node = node0 + nn;
        float4 a = make_float4(0.f, 0.f, 0.f, 0.f), hh = a;
        if (node < N) { a = agg4[(size_t)node * 32 + f4]; hh = hin4[(size_t)node * 32 + f4]; }
        ((float4*)sA[nn])[f4] = a;
        ((float4*)sB[nn])[f4] = hh;
    }
    __syncthreads();
    float acc[2][8];
    sage_tile_gemm(sA, sB, Wl, Wr, b, (int)threadIdx.x, acc);
    __syncthreads();   // all reads of sA/sB done; reuse sA for h1 tile
    int c = threadIdx.x & 15;
    int ng = threadIdx.x >> 4;
#pragma unroll
    for (int q = 0; q < 2; ++q) {
        int nn = ng * 2 + q;
        float4 o0 = make_float4(fmaxf(acc[q][0], 0.f), fmaxf(acc[q][1], 0.f),
                                fmaxf(acc[q][2], 0.f), fmaxf(acc[q][3], 0.f));
        float4 o1 = make_float4(fmaxf(acc[q][4], 0.f), fmaxf(acc[q][5], 0.f),
                                fmaxf(acc[q][6], 0.f), fmaxf(acc[q][7], 0.f));
        ((float4*)sA[nn])[c * 2] = o0;
        ((float4*)sA[nn])[c * 2 + 1] = o1;
    }
    __syncthreads();

    // out stage: 64 cols = 1 wave; wave wv handles nodes wv*8..wv*8+7.
    int j2 = threadIdx.x & 63;
    int wv = threadIdx.x >> 6;   // 0..3
    float o[8];
    float bo = bout[j2];
#pragma unroll
    for (int q = 0; q < 8; ++q) o[q] = bo;
    for (int k4 = 0; k4 < 32; ++k4) {
        float w[4];
#pragma unroll
        for (int u = 0; u < 4; ++u) w[u] = Wout[(k4 * 4 + u) * 64 + j2];
#pragma unroll
        for (int q = 0; q < 8; ++q) {
            float4 hv = ((const float4*)sA[wv * 8 + q])[k4];
            o[q] += hv.x * w[0] + hv.y * w[1] + hv.z * w[2] + hv.w * w[3];
        }
    }
#pragma unroll
    for (int q = 0; q < 8; ++q) {
        float m = o[q];
#pragma unroll
        for (int ofs = 32; ofs; ofs >>= 1) m = fmaxf(m, __shfl_xor(m, ofs, 64));
        float e = __expf(o[q] - m);
        float s = e;
#pragma unroll
        for (int ofs = 32; ofs; ofs >>= 1) s += __shfl_xor(s, ofs, 64);
        int node = node0 + wv * 8 + q;
        if (node < N) out[(size_t)node * 64 + j2] = e / s;
    }
}

extern "C" void kernel_launch(void* const* d_in, const int* in_sizes, int n_in,
                              void* d_out, int out_size, void* d_ws, size_t ws_size,
                              hipStream_t stream) {
    const float* x    = (const float*)d_in[0];
    const int*   ei   = (const int*)d_in[1];
    const float* Wl0  = (const float*)d_in[2];
    const float* Wr0  = (const float*)d_in[3];
    const float* b0   = (const float*)d_in[4];
    const float* Wl1  = (const float*)d_in[5];
    const float* Wr1  = (const float*)d_in[6];
    const float* b1   = (const float*)d_in[7];
    const float* Wout = (const float*)d_in[8];
    const float* bout = (const float*)d_in[9];

    int N = in_sizes[0] / 128;
    int E = in_sizes[1] / 2;
    const int* src = ei;
    const int* dst = ei + E;
    int P = (N + CHUNK - 1) / CHUNK;

    char* p = (char*)d_ws;
    auto alloc = [&](size_t bytes) -> char* {
        char* r = p;
        p += (bytes + 255) & ~(size_t)255;
        return r;
    };
    int*   cnt     = (int*)alloc((size_t)N * 4);
    int*   cursor  = (int*)alloc((size_t)N * 4);
    int*   off     = (int*)alloc((size_t)(N + 1) * 4);
    int*   csr     = (int*)alloc((size_t)E * 4);
    int*   partial = (int*)alloc((size_t)P * 4);
    int*   baseA   = (int*)alloc((size_t)P * 4);
    float* agg     = (float*)alloc((size_t)N * 128 * 4);
    float* h0      = (float*)alloc((size_t)N * 128 * 4);

    hipMemsetAsync(cnt, 0, (size_t)N * 4, stream);
    hipMemsetAsync(cursor, 0, (size_t)N * 4, stream);

    int eb = (E + 255) / 256;
    count_kernel<<<eb, 256, 0, stream>>>(dst, cnt, E, N);
    scan_partial_kernel<<<P, 256, 0, stream>>>(cnt, partial, N);
    scan_base_kernel<<<1, 64, 0, stream>>>(partial, baseA, off, P, N);
    scan_chunk_kernel<<<P, 256, 0, stream>>>(cnt, baseA, off, N);
    fill_kernel<<<eb, 256, 0, stream>>>(src, dst, off, cursor, csr, E, N);

    int ab = (N * 32 + 255) / 256;   // aggregate: 32 lanes/node
    int lb = (N + 31) / 32;          // linear: 32 nodes/block

    aggregate_kernel<<<ab, 256, 0, stream>>>(x, off, csr, agg, N);
    sage_linear_kernel<<<lb, 256, 0, stream>>>(agg, x, Wl0, Wr0, b0, h0, N);
    aggregate_kernel<<<ab, 256, 0, stream>>>(h0, off, csr, agg, N);
    sage_linear_out_kernel<<<lb, 256, 0, stream>>>(agg, h0, Wl1, Wr1, b1, Wout, bout,
                                                   (float*)d_out, N);
}

// Round 4
// 439.295 us; speedup vs baseline: 1.1933x; 1.1933x over previous
//
#include <hip/hip_runtime.h>

// GraphSAGE: 2x SAGEConv(mean) + Linear + softmax. fp32 throughout.
// Pipeline: CSR build (count / 3-phase scan / fill)
//           -> fused[aggregate+linear1+ReLU] -> fused[aggregate+linear2+out+softmax].
// GEMM tiling: block = 32 nodes x 128 cols; thread = 4 nodes x 4 ADJACENT cols.
//   - weight loads: float4 at W4[k*32+c], c=tid&31 -> coalesced 16B/lane
//   - LDS reads: 2 distinct rows per wave instruction -> 2-way alias = free (m136)
//   - per k4: 8 ds_read_b128 (96cyc) vs 128 FMA (256cyc) -> VALU-bound

#define CHUNK 2048   // elements per scan block (256 threads x 8)

__global__ void count_kernel(const int* __restrict__ dst, int* __restrict__ cnt, int E, int N) {
    int e = blockIdx.x * blockDim.x + threadIdx.x;
    if (e < E) {
        int d = dst[e];
        if ((unsigned)d < (unsigned)N) atomicAdd(&cnt[d], 1);
    }
}

// Phase A: per-chunk sums.
__global__ __launch_bounds__(256) void scan_partial_kernel(const int* __restrict__ cnt,
                                                           int* __restrict__ partial, int n) {
    __shared__ int ws[4];
    int base = blockIdx.x * CHUNK + (int)threadIdx.x * 8;
    int s = 0;
#pragma unroll
    for (int u = 0; u < 8; ++u) {
        int i = base + u;
        if (i < n) s += cnt[i];
    }
#pragma unroll
    for (int o = 32; o; o >>= 1) s += __shfl_xor(s, o, 64);
    int lane = threadIdx.x & 63, wv = threadIdx.x >> 6;
    if (lane == 0) ws[wv] = s;
    __syncthreads();
    if (threadIdx.x == 0) partial[blockIdx.x] = ws[0] + ws[1] + ws[2] + ws[3];
}

// Phase B: 1 wave scans the partials (P ~ 25), writes per-chunk bases + off[n].
__global__ void scan_base_kernel(const int* __restrict__ partial, int* __restrict__ baseArr,
                                 int* __restrict__ off, int P, int n) {
    int lane = threadIdx.x;   // blockDim = 64
    int running = 0;
    for (int b0 = 0; b0 < P; b0 += 64) {
        int i = b0 + lane;
        int v = (i < P) ? partial[i] : 0;
        int s = v;
#pragma unroll
        for (int o = 1; o < 64; o <<= 1) {
            int t = __shfl_up(s, o, 64);
            if (lane >= o) s += t;
        }
        if (i < P) baseArr[i] = running + s - v;
        running += __shfl(s, 63, 64);
    }
    if (lane == 0) off[n] = running;
}

// Phase C: per-chunk exclusive scan + base.
__global__ __launch_bounds__(256) void scan_chunk_kernel(const int* __restrict__ cnt,
                                                         const int* __restrict__ baseArr,
                                                         int* __restrict__ off, int n) {
    __shared__ int wsum[4];
    int lane = threadIdx.x & 63, wv = threadIdx.x >> 6;
    int i0 = blockIdx.x * CHUNK + (int)threadIdx.x * 8;
    int v[8];
    int ts = 0;
#pragma unroll
    for (int u = 0; u < 8; ++u) {
        int i = i0 + u;
        v[u] = (i < n) ? cnt[i] : 0;
        ts += v[u];
    }
    int s = ts;
#pragma unroll
    for (int o = 1; o < 64; o <<= 1) {
        int t = __shfl_up(s, o, 64);
        if (lane >= o) s += t;
    }
    if (lane == 63) wsum[wv] = s;
    __syncthreads();
    int run = baseArr[blockIdx.x];
    for (int w = 0; w < wv; ++w) run += wsum[w];
    run += s - ts;   // exclusive prefix for this thread's first element
#pragma unroll
    for (int u = 0; u < 8; ++u) {
        int i = i0 + u;
        if (i < n) off[i] = run;
        run += v[u];
    }
}

__global__ void fill_kernel(const int* __restrict__ src, const int* __restrict__ dstp,
                            const int* __restrict__ off, int* __restrict__ cursor,
                            int* __restrict__ csr, int E, int N) {
    int e = blockIdx.x * blockDim.x + threadIdx.x;
    if (e < E) {
        int d = dstp[e];
        int s = src[e];
        if ((unsigned)d < (unsigned)N) {
            int pos = atomicAdd(&cursor[d], 1);
            csr[off[d] + pos] = ((unsigned)s < (unsigned)N) ? s : 0;
        }
    }
}

// Phase 1 of fused kernels: mean-aggregate 32 nodes into sA, stage hin rows into sB.
// Half-wave (32 lanes) per node, float4 per lane, 2 independent accumulators.
__device__ __forceinline__ void sage_agg_stage(
        const float* __restrict__ hin, const int* __restrict__ off,
        const int* __restrict__ csr, int node0, int N,
        float (*sA)[128], float (*sB)[128], int tid) {
    int lane = tid & 31;
    int sub = tid >> 5;   // 0..7: which node of the group of 8
    const float4* h4 = (const float4*)hin;
    for (int nt = 0; nt < 4; ++nt) {
        int nn = nt * 8 + sub;
        int node = node0 + nn;
        float4 a0 = make_float4(0.f, 0.f, 0.f, 0.f);
        float4 a1 = a0, hh = a0;
        if (node < N) {
            int s0 = off[node], s1 = off[node + 1];
            int e = s0;
            for (; e + 2 <= s1; e += 2) {
                int i0 = csr[e], i1 = csr[e + 1];
                float4 v0 = h4[(size_t)i0 * 32 + lane];
                float4 v1 = h4[(size_t)i1 * 32 + lane];
                a0.x += v0.x; a0.y += v0.y; a0.z += v0.z; a0.w += v0.w;
                a1.x += v1.x; a1.y += v1.y; a1.z += v1.z; a1.w += v1.w;
            }
            if (e < s1) {
                int i0 = csr[e];
                float4 v0 = h4[(size_t)i0 * 32 + lane];
                a0.x += v0.x; a0.y += v0.y; a0.z += v0.z; a0.w += v0.w;
            }
            float inv = 1.0f / (float)max(s1 - s0, 1);
            a0.x = (a0.x + a1.x) * inv; a0.y = (a0.y + a1.y) * inv;
            a0.z = (a0.z + a1.z) * inv; a0.w = (a0.w + a1.w) * inv;
            hh = h4[(size_t)node * 32 + lane];
        }
        ((float4*)sA[nn])[lane] = a0;
        ((float4*)sB[nn])[lane] = hh;
    }
}

// GEMM core: acc[n][cc] for nodes 4g..4g+3, cols 4c..4c+3.
__device__ __forceinline__ void sage_tile_gemm(
        const float (*sA)[128], const float (*sB)[128],
        const float* __restrict__ Wl, const float* __restrict__ Wr,
        const float* __restrict__ b, int tid, float acc[4][4]) {
    int c = tid & 31;
    int g = tid >> 5;
    const float4* Wl4 = (const float4*)Wl;
    const float4* Wr4 = (const float4*)Wr;
    float4 bj = ((const float4*)b)[c];
#pragma unroll
    for (int n = 0; n < 4; ++n) {
        acc[n][0] = bj.x; acc[n][1] = bj.y; acc[n][2] = bj.z; acc[n][3] = bj.w;
    }
    for (int k4 = 0; k4 < 32; ++k4) {
        float4 a[4], h[4];
#pragma unroll
        for (int n = 0; n < 4; ++n) {
            a[n] = ((const float4*)sA[g * 4 + n])[k4];
            h[n] = ((const float4*)sB[g * 4 + n])[k4];
        }
        float4 wl[4], wr[4];
#pragma unroll
        for (int u = 0; u < 4; ++u) {
            wl[u] = Wl4[(k4 * 4 + u) * 32 + c];
            wr[u] = Wr4[(k4 * 4 + u) * 32 + c];
        }
#pragma unroll
        for (int u = 0; u < 4; ++u) {
#pragma unroll
            for (int n = 0; n < 4; ++n) {
                float au = ((const float*)&a[n])[u];
                float hu = ((const float*)&h[n])[u];
                acc[n][0] += au * wl[u].x + hu * wr[u].x;
                acc[n][1] += au * wl[u].y + hu * wr[u].y;
                acc[n][2] += au * wl[u].z + hu * wr[u].z;
                acc[n][3] += au * wl[u].w + hu * wr[u].w;
            }
        }
    }
}

// Fused: aggregate + hout = relu(agg @ Wl + hin @ Wr + b).
__global__ __launch_bounds__(256) void sage_layer_kernel(
        const float* __restrict__ hin, const int* __restrict__ off,
        const int* __restrict__ csr,
        const float* __restrict__ Wl, const float* __restrict__ Wr,
        const float* __restrict__ b, float* __restrict__ hout, int N) {
    __shared__ float sA[32][128];
    __shared__ float sB[32][128];
    int node0 = blockIdx.x * 32;
    sage_agg_stage(hin, off, csr, node0, N, sA, sB, (int)threadIdx.x);
    __syncthreads();
    float acc[4][4];
    sage_tile_gemm(sA, sB, Wl, Wr, b, (int)threadIdx.x, acc);
    int c = threadIdx.x & 31;
    int g = threadIdx.x >> 5;
#pragma unroll
    for (int n = 0; n < 4; ++n) {
        int node = node0 + g * 4 + n;
        if (node < N) {
            float4 o = make_float4(fmaxf(acc[n][0], 0.f), fmaxf(acc[n][1], 0.f),
                                   fmaxf(acc[n][2], 0.f), fmaxf(acc[n][3], 0.f));
            ((float4*)(hout + (size_t)node * 128))[c] = o;
        }
    }
}

// Fused: aggregate + layer2 + output projection + softmax.
__global__ __launch_bounds__(256) void sage_layer_out_kernel(
        const float* __restrict__ hin, const int* __restrict__ off,
        const int* __restrict__ csr,
        const float* __restrict__ Wl, const float* __restrict__ Wr,
        const float* __restrict__ b, const float* __restrict__ Wout,
        const float* __restrict__ bout, float* __restrict__ out, int N) {
    __shared__ float sA[32][128];
    __shared__ float sB[32][128];
    int node0 = blockIdx.x * 32;
    sage_agg_stage(hin, off, csr, node0, N, sA, sB, (int)threadIdx.x);
    __syncthreads();
    float acc[4][4];
    sage_tile_gemm(sA, sB, Wl, Wr, b, (int)threadIdx.x, acc);
    __syncthreads();   // all reads of sA/sB done; reuse sA for h1 tile
    int c = threadIdx.x & 31;
    int g = threadIdx.x >> 5;
#pragma unroll
    for (int n = 0; n < 4; ++n) {
        float4 o = make_float4(fmaxf(acc[n][0], 0.f), fmaxf(acc[n][1], 0.f),
                               fmaxf(acc[n][2], 0.f), fmaxf(acc[n][3], 0.f));
        ((float4*)sA[g * 4 + n])[c] = o;
    }
    __syncthreads();

    // out stage: 64 cols = 1 wave; wave wv handles nodes wv*8..wv*8+7.
    int j2 = threadIdx.x & 63;
    int wv = threadIdx.x >> 6;   // 0..3
    float o[8];
    float bo = bout[j2];
#pragma unroll
    for (int q = 0; q < 8; ++q) o[q] = bo;
    for (int k4 = 0; k4 < 32; ++k4) {
        float w[4];
#pragma unroll
        for (int u = 0; u < 4; ++u) w[u] = Wout[(k4 * 4 + u) * 64 + j2];
#pragma unroll
        for (int q = 0; q < 8; ++q) {
            float4 hv = ((const float4*)sA[wv * 8 + q])[k4];
            o[q] += hv.x * w[0] + hv.y * w[1] + hv.z * w[2] + hv.w * w[3];
        }
    }
#pragma unroll
    for (int q = 0; q < 8; ++q) {
        float m = o[q];
#pragma unroll
        for (int ofs = 32; ofs; ofs >>= 1) m = fmaxf(m, __shfl_xor(m, ofs, 64));
        float e = __expf(o[q] - m);
        float s = e;
#pragma unroll
        for (int ofs = 32; ofs; ofs >>= 1) s += __shfl_xor(s, ofs, 64);
        int node = node0 + wv * 8 + q;
        if (node < N) out[(size_t)node * 64 + j2] = e / s;
    }
}

extern "C" void kernel_launch(void* const* d_in, const int* in_sizes, int n_in,
                              void* d_out, int out_size, void* d_ws, size_t ws_size,
                              hipStream_t stream) {
    const float* x    = (const float*)d_in[0];
    const int*   ei   = (const int*)d_in[1];
    const float* Wl0  = (const float*)d_in[2];
    const float* Wr0  = (const float*)d_in[3];
    const float* b0   = (const float*)d_in[4];
    const float* Wl1  = (const float*)d_in[5];
    const float* Wr1  = (const float*)d_in[6];
    const float* b1   = (const float*)d_in[7];
    const float* Wout = (const float*)d_in[8];
    const float* bout = (const float*)d_in[9];

    int N = in_sizes[0] / 128;
    int E = in_sizes[1] / 2;
    const int* src = ei;
    const int* dst = ei + E;
    int P = (N + CHUNK - 1) / CHUNK;

    char* p = (char*)d_ws;
    auto alloc = [&](size_t bytes) -> char* {
        char* r = p;
        p += (bytes + 255) & ~(size_t)255;
        return r;
    };
    int*   cnt     = (int*)alloc((size_t)N * 4);
    int*   cursor  = (int*)alloc((size_t)N * 4);
    int*   off     = (int*)alloc((size_t)(N + 1) * 4);
    int*   csr     = (int*)alloc((size_t)E * 4);
    int*   partial = (int*)alloc((size_t)P * 4);
    int*   baseA   = (int*)alloc((size_t)P * 4);
    float* h0      = (float*)alloc((size_t)N * 128 * 4);

    hipMemsetAsync(cnt, 0, (size_t)N * 4, stream);
    hipMemsetAsync(cursor, 0, (size_t)N * 4, stream);

    int eb = (E + 255) / 256;
    count_kernel<<<eb, 256, 0, stream>>>(dst, cnt, E, N);
    scan_partial_kernel<<<P, 256, 0, stream>>>(cnt, partial, N);
    scan_base_kernel<<<1, 64, 0, stream>>>(partial, baseA, off, P, N);
    scan_chunk_kernel<<<P, 256, 0, stream>>>(cnt, baseA, off, N);
    fill_kernel<<<eb, 256, 0, stream>>>(src, dst, off, cursor, csr, E, N);

    int lb = (N + 31) / 32;   // fused layer: 32 nodes/block

    sage_layer_kernel<<<lb, 256, 0, stream>>>(x, off, csr, Wl0, Wr0, b0, h0, N);
    sage_layer_out_kernel<<<lb, 256, 0, stream>>>(h0, off, csr, Wl1, Wr1, b1,
                                                  Wout, bout, (float*)d_out, N);
}

// Round 5
// 410.249 us; speedup vs baseline: 1.2778x; 1.0708x over previous
//
#include <hip/hip_runtime.h>

// GraphSAGE: 2x SAGEConv(mean) + Linear + softmax. fp32 throughout.
// Pipeline: CSR build (count / 3-phase scan / fill)
//           -> fused[aggregate+linear1+ReLU] -> fused[aggregate+linear2+out+softmax].
// GEMM tiling: block = 32 nodes x 128 cols; thread = 4 nodes x 4 ADJACENT cols.
// Aggregation: half-wave per node; 32 neighbor indices loaded in ONE coalesced
// vector load, broadcast via in-register __shfl(width=32); 8 independent
// gathers in flight per step (latency -> throughput bound).

#define CHUNK 2048   // elements per scan block (256 threads x 8)

__global__ void count_kernel(const int* __restrict__ dst, int* __restrict__ cnt, int E, int N) {
    int e = blockIdx.x * blockDim.x + threadIdx.x;
    if (e < E) {
        int d = dst[e];
        if ((unsigned)d < (unsigned)N) atomicAdd(&cnt[d], 1);
    }
}

// Phase A: per-chunk sums.
__global__ __launch_bounds__(256) void scan_partial_kernel(const int* __restrict__ cnt,
                                                           int* __restrict__ partial, int n) {
    __shared__ int ws[4];
    int base = blockIdx.x * CHUNK + (int)threadIdx.x * 8;
    int s = 0;
#pragma unroll
    for (int u = 0; u < 8; ++u) {
        int i = base + u;
        if (i < n) s += cnt[i];
    }
#pragma unroll
    for (int o = 32; o; o >>= 1) s += __shfl_xor(s, o, 64);
    int lane = threadIdx.x & 63, wv = threadIdx.x >> 6;
    if (lane == 0) ws[wv] = s;
    __syncthreads();
    if (threadIdx.x == 0) partial[blockIdx.x] = ws[0] + ws[1] + ws[2] + ws[3];
}

// Phase B: 1 wave scans the partials (P ~ 25), writes per-chunk bases + off[n].
__global__ void scan_base_kernel(const int* __restrict__ partial, int* __restrict__ baseArr,
                                 int* __restrict__ off, int P, int n) {
    int lane = threadIdx.x;   // blockDim = 64
    int running = 0;
    for (int b0 = 0; b0 < P; b0 += 64) {
        int i = b0 + lane;
        int v = (i < P) ? partial[i] : 0;
        int s = v;
#pragma unroll
        for (int o = 1; o < 64; o <<= 1) {
            int t = __shfl_up(s, o, 64);
            if (lane >= o) s += t;
        }
        if (i < P) baseArr[i] = running + s - v;
        running += __shfl(s, 63, 64);
    }
    if (lane == 0) off[n] = running;
}

// Phase C: per-chunk exclusive scan + base.
__global__ __launch_bounds__(256) void scan_chunk_kernel(const int* __restrict__ cnt,
                                                         const int* __restrict__ baseArr,
                                                         int* __restrict__ off, int n) {
    __shared__ int wsum[4];
    int lane = threadIdx.x & 63, wv = threadIdx.x >> 6;
    int i0 = blockIdx.x * CHUNK + (int)threadIdx.x * 8;
    int v[8];
    int ts = 0;
#pragma unroll
    for (int u = 0; u < 8; ++u) {
        int i = i0 + u;
        v[u] = (i < n) ? cnt[i] : 0;
        ts += v[u];
    }
    int s = ts;
#pragma unroll
    for (int o = 1; o < 64; o <<= 1) {
        int t = __shfl_up(s, o, 64);
        if (lane >= o) s += t;
    }
    if (lane == 63) wsum[wv] = s;
    __syncthreads();
    int run = baseArr[blockIdx.x];
    for (int w = 0; w < wv; ++w) run += wsum[w];
    run += s - ts;   // exclusive prefix for this thread's first element
#pragma unroll
    for (int u = 0; u < 8; ++u) {
        int i = i0 + u;
        if (i < n) off[i] = run;
        run += v[u];
    }
}

__global__ void fill_kernel(const int* __restrict__ src, const int* __restrict__ dstp,
                            const int* __restrict__ off, int* __restrict__ cursor,
                            int* __restrict__ csr, int E, int N) {
    int e = blockIdx.x * blockDim.x + threadIdx.x;
    if (e < E) {
        int d = dstp[e];
        int s = src[e];
        if ((unsigned)d < (unsigned)N) {
            int pos = atomicAdd(&cursor[d], 1);
            csr[off[d] + pos] = ((unsigned)s < (unsigned)N) ? s : 0;
        }
    }
}

// Mean-aggregate 32 nodes into sA, stage hin rows into sB.
// Half-wave (32 lanes) per node. Per 32-edge chunk: 1 coalesced index load,
// then 8 independent gathers per unrolled step (shfl broadcast, no mem op).
__device__ __forceinline__ void sage_agg_stage(
        const float* __restrict__ hin, const int* __restrict__ off,
        const int* __restrict__ csr, int node0, int N,
        float (*sA)[128], float (*sB)[128], int tid) {
    int lane = tid & 31;
    int sub = tid >> 5;   // 0..7: which node of the group of 8
    const float4* h4 = (const float4*)hin;
    for (int nt = 0; nt < 4; ++nt) {
        int nn = nt * 8 + sub;
        int node = node0 + nn;
        float4 a0 = make_float4(0.f, 0.f, 0.f, 0.f);
        float4 a1 = a0, hh = a0;
        if (node < N) {
            int s0 = off[node], s1 = off[node + 1];
            int deg = s1 - s0;
            for (int base = 0; base < deg; base += 32) {
                int nc = min(32, deg - base);
                int e = min(s0 + base + lane, s1 - 1);   // clamped: safe, convergent
                int idx = csr[e];
                for (int j = 0; j < nc; j += 8) {
                    float4 v[8];
#pragma unroll
                    for (int u = 0; u < 8; ++u) {
                        int sl = j + u;                  // <= 31 always (nc<=32, j%8==0)
                        int sidx = __shfl(idx, sl, 32);
                        v[u] = h4[(size_t)sidx * 32 + lane];
                    }
#pragma unroll
                    for (int u = 0; u < 8; ++u) {
                        float m = (j + u < nc) ? 1.f : 0.f;   // mask tail, keep 8 in flight
                        float4* acc = (u & 1) ? &a1 : &a0;
                        acc->x += v[u].x * m; acc->y += v[u].y * m;
                        acc->z += v[u].z * m; acc->w += v[u].w * m;
                    }
                }
            }
            float inv = 1.0f / (float)max(deg, 1);
            a0.x = (a0.x + a1.x) * inv; a0.y = (a0.y + a1.y) * inv;
            a0.z = (a0.z + a1.z) * inv; a0.w = (a0.w + a1.w) * inv;
            hh = h4[(size_t)node * 32 + lane];
        }
        ((float4*)sA[nn])[lane] = a0;
        ((float4*)sB[nn])[lane] = hh;
    }
}

// GEMM core: acc[n][cc] for nodes 4g..4g+3, cols 4c..4c+3.
__device__ __forceinline__ void sage_tile_gemm(
        const float (*sA)[128], const float (*sB)[128],
        const float* __restrict__ Wl, const float* __restrict__ Wr,
        const float* __restrict__ b, int tid, float acc[4][4]) {
    int c = tid & 31;
    int g = tid >> 5;
    const float4* Wl4 = (const float4*)Wl;
    const float4* Wr4 = (const float4*)Wr;
    float4 bj = ((const float4*)b)[c];
#pragma unroll
    for (int n = 0; n < 4; ++n) {
        acc[n][0] = bj.x; acc[n][1] = bj.y; acc[n][2] = bj.z; acc[n][3] = bj.w;
    }
    for (int k4 = 0; k4 < 32; ++k4) {
        float4 a[4], h[4];
#pragma unroll
        for (int n = 0; n < 4; ++n) {
            a[n] = ((const float4*)sA[g * 4 + n])[k4];
            h[n] = ((const float4*)sB[g * 4 + n])[k4];
        }
        float4 wl[4], wr[4];
#pragma unroll
        for (int u = 0; u < 4; ++u) {
            wl[u] = Wl4[(k4 * 4 + u) * 32 + c];
            wr[u] = Wr4[(k4 * 4 + u) * 32 + c];
        }
#pragma unroll
        for (int u = 0; u < 4; ++u) {
#pragma unroll
            for (int n = 0; n < 4; ++n) {
                float au = ((const float*)&a[n])[u];
                float hu = ((const float*)&h[n])[u];
                acc[n][0] += au * wl[u].x + hu * wr[u].x;
                acc[n][1] += au * wl[u].y + hu * wr[u].y;
                acc[n][2] += au * wl[u].z + hu * wr[u].z;
                acc[n][3] += au * wl[u].w + hu * wr[u].w;
            }
        }
    }
}

// Fused: aggregate + hout = relu(agg @ Wl + hin @ Wr + b).
__global__ __launch_bounds__(256, 4) void sage_layer_kernel(
        const float* __restrict__ hin, const int* __restrict__ off,
        const int* __restrict__ csr,
        const float* __restrict__ Wl, const float* __restrict__ Wr,
        const float* __restrict__ b, float* __restrict__ hout, int N) {
    __shared__ float sA[32][128];
    __shared__ float sB[32][128];
    int node0 = blockIdx.x * 32;
    sage_agg_stage(hin, off, csr, node0, N, sA, sB, (int)threadIdx.x);
    __syncthreads();
    float acc[4][4];
    sage_tile_gemm(sA, sB, Wl, Wr, b, (int)threadIdx.x, acc);
    int c = threadIdx.x & 31;
    int g = threadIdx.x >> 5;
#pragma unroll
    for (int n = 0; n < 4; ++n) {
        int node = node0 + g * 4 + n;
        if (node < N) {
            float4 o = make_float4(fmaxf(acc[n][0], 0.f), fmaxf(acc[n][1], 0.f),
                                   fmaxf(acc[n][2], 0.f), fmaxf(acc[n][3], 0.f));
            ((float4*)(hout + (size_t)node * 128))[c] = o;
        }
    }
}

// Fused: aggregate + layer2 + output projection + softmax.
__global__ __launch_bounds__(256, 4) void sage_layer_out_kernel(
        const float* __restrict__ hin, const int* __restrict__ off,
        const int* __restrict__ csr,
        const float* __restrict__ Wl, const float* __restrict__ Wr,
        const float* __restrict__ b, const float* __restrict__ Wout,
        const float* __restrict__ bout, float* __restrict__ out, int N) {
    __shared__ float sA[32][128];
    __shared__ float sB[32][128];
    int node0 = blockIdx.x * 32;
    sage_agg_stage(hin, off, csr, node0, N, sA, sB, (int)threadIdx.x);
    __syncthreads();
    float acc[4][4];
    sage_tile_gemm(sA, sB, Wl, Wr, b, (int)threadIdx.x, acc);
    __syncthreads();   // all reads of sA/sB done; reuse sA for h1 tile
    int c = threadIdx.x & 31;
    int g = threadIdx.x >> 5;
#pragma unroll
    for (int n = 0; n < 4; ++n) {
        float4 o = make_float4(fmaxf(acc[n][0], 0.f), fmaxf(acc[n][1], 0.f),
                               fmaxf(acc[n][2], 0.f), fmaxf(acc[n][3], 0.f));
        ((float4*)sA[g * 4 + n])[c] = o;
    }
    __syncthreads();

    // out stage: 64 cols = 1 wave; wave wv handles nodes wv*8..wv*8+7.
    int j2 = threadIdx.x & 63;
    int wv = threadIdx.x >> 6;   // 0..3
    float o[8];
    float bo = bout[j2];
#pragma unroll
    for (int q = 0; q < 8; ++q) o[q] = bo;
    for (int k4 = 0; k4 < 32; ++k4) {
        float w[4];
#pragma unroll
        for (int u = 0; u < 4; ++u) w[u] = Wout[(k4 * 4 + u) * 64 + j2];
#pragma unroll
        for (int q = 0; q < 8; ++q) {
            float4 hv = ((const float4*)sA[wv * 8 + q])[k4];
            o[q] += hv.x * w[0] + hv.y * w[1] + hv.z * w[2] + hv.w * w[3];
        }
    }
#pragma unroll
    for (int q = 0; q < 8; ++q) {
        float m = o[q];
#pragma unroll
        for (int ofs = 32; ofs; ofs >>= 1) m = fmaxf(m, __shfl_xor(m, ofs, 64));
        float e = __expf(o[q] - m);
        float s = e;
#pragma unroll
        for (int ofs = 32; ofs; ofs >>= 1) s += __shfl_xor(s, ofs, 64);
        int node = node0 + wv * 8 + q;
        if (node < N) out[(size_t)node * 64 + j2] = e / s;
    }
}

extern "C" void kernel_launch(void* const* d_in, const int* in_sizes, int n_in,
                              void* d_out, int out_size, void* d_ws, size_t ws_size,
                              hipStream_t stream) {
    const float* x    = (const float*)d_in[0];
    const int*   ei   = (const int*)d_in[1];
    const float* Wl0  = (const float*)d_in[2];
    const float* Wr0  = (const float*)d_in[3];
    const float* b0   = (const float*)d_in[4];
    const float* Wl1  = (const float*)d_in[5];
    const float* Wr1  = (const float*)d_in[6];
    const float* b1   = (const float*)d_in[7];
    const float* Wout = (const float*)d_in[8];
    const float* bout = (const float*)d_in[9];

    int N = in_sizes[0] / 128;
    int E = in_sizes[1] / 2;
    const int* src = ei;
    const int* dst = ei + E;
    int P = (N + CHUNK - 1) / CHUNK;

    char* p = (char*)d_ws;
    auto alloc = [&](size_t bytes) -> char* {
        char* r = p;
        p += (bytes + 255) & ~(size_t)255;
        return r;
    };
    int*   cnt     = (int*)alloc((size_t)N * 4);
    int*   cursor  = (int*)alloc((size_t)N * 4);
    int*   off     = (int*)alloc((size_t)(N + 1) * 4);
    int*   csr     = (int*)alloc((size_t)E * 4);
    int*   partial = (int*)alloc((size_t)P * 4);
    int*   baseA   = (int*)alloc((size_t)P * 4);
    float* h0      = (float*)alloc((size_t)N * 128 * 4);

    hipMemsetAsync(cnt, 0, (size_t)N * 4, stream);
    hipMemsetAsync(cursor, 0, (size_t)N * 4, stream);

    int eb = (E + 255) / 256;
    count_kernel<<<eb, 256, 0, stream>>>(dst, cnt, E, N);
    scan_partial_kernel<<<P, 256, 0, stream>>>(cnt, partial, N);
    scan_base_kernel<<<1, 64, 0, stream>>>(partial, baseA, off, P, N);
    scan_chunk_kernel<<<P, 256, 0, stream>>>(cnt, baseA, off, N);
    fill_kernel<<<eb, 256, 0, stream>>>(src, dst, off, cursor, csr, E, N);

    int lb = (N + 31) / 32;   // fused layer: 32 nodes/block

    sage_layer_kernel<<<lb, 256, 0, stream>>>(x, off, csr, Wl0, Wr0, b0, h0, N);
    sage_layer_out_kernel<<<lb, 256, 0, stream>>>(h0, off, csr, Wl1, Wr1, b1,
                                                  Wout, bout, (float*)d_out, N);
}